// Round 8
// baseline (455.416 us; speedup 1.0000x reference)
//
#include <hip/hip_runtime.h>
#include <hip/hip_bf16.h>

#define N_NODES 100000
#define N_EDGES 1600000
#define FEAT 128
#define N_GRAPHS 1024
#define NBUCK 391   // ceil(N_NODES/256) windows of 256 nodes (window = node >> 8)
#define CHUNK 4096  // edges per fill block
#define NTILES 1563 // ceil(N_NODES/64) gemm row tiles

typedef short short8 __attribute__((ext_vector_type(8)));
typedef float float4v __attribute__((ext_vector_type(4)));

static __device__ inline unsigned short f2bf(float f) {
    __hip_bfloat16 b = __float2bfloat16(f);
    unsigned short r;
    __builtin_memcpy(&r, &b, 2);
    return r;
}
static __device__ inline float bf_lo(unsigned int v) { return __uint_as_float(v << 16); }
static __device__ inline float bf_hi(unsigned int v) { return __uint_as_float(v & 0xFFFF0000u); }

// ---------------- dispatch 1: W-split prep (blocks 0..127) + window hist + per-node deg ----------
// Hist blocks (128..383) now ALSO atomicAdd deg[dst] (fire-and-forget, 1.6M atomics over 100K
// addresses = ~16 deep/address — contention-safe, unlike round-2's 25-line pileup).
__global__ __launch_bounds__(256) void k_prep_hist(const float* __restrict__ W1,
                                                   const float* __restrict__ W2,
                                                   unsigned short* __restrict__ wp1,
                                                   unsigned short* __restrict__ wp2,
                                                   const int* __restrict__ dst,
                                                   int* __restrict__ bcount,
                                                   int* __restrict__ deg,
                                                   unsigned int* __restrict__ udummy,
                                                   unsigned int* __restrict__ u2dummy,
                                                   float* __restrict__ dinv) {
    int bid = blockIdx.x;
    if (bid < 128) {
        const float* W = (bid < 64) ? W1 : W2;
        unsigned short* wp = (bid < 64) ? wp1 : wp2;
        int t = (bid & 63) * 256 + threadIdx.x;  // 0..16383
        int k = t >> 7, n = t & 127;
        float w = W[k * 128 + n];
        unsigned ub = __float_as_uint(w);
        unsigned short hi = (unsigned short)(ub >> 16);  // truncation split
        float hif = __uint_as_float(ub & 0xFFFF0000u);
        unsigned short lo = f2bf(w - hif);               // RNE residual
        int sidx = n * 128 + ((k & 7) | (8 * (((k >> 3) ^ n) & 15)));
        wp[sidx] = hi;
        wp[16384 + sidx] = lo;
        if (bid == 0) {
            if (threadIdx.x < 64) udummy[threadIdx.x] = 0;
            else if (threadIdx.x < 128) u2dummy[threadIdx.x - 64] = 0;
            else if (threadIdx.x == 128) dinv[N_NODES] = 0.f;
        }
    } else {
        __shared__ int h[NBUCK];
        for (int i = threadIdx.x; i < NBUCK; i += 256) h[i] = 0;
        __syncthreads();
        int hb = bid - 128;
        for (int e = hb * 256 + threadIdx.x; e < N_EDGES; e += 256 * 256) {
            int d = dst[e];
            atomicAdd(&h[d >> 8], 1);
            atomicAdd(&deg[d], 1);   // global, no return value -> fire-and-forget
        }
        __syncthreads();
        for (int i = threadIdx.x; i < NBUCK; i += 256) {
            int c = h[i];
            if (c) atomicAdd(&bcount[i], c);
        }
    }
}

// ---------------- dispatch 2: offs/cur/dinv (391 blocks; window base computed in-block) --------
// Replaces the old scan391 dispatch + bfill's scan: each block reduces bcount[w<b] itself
// (391 ints from L2, ~free), then intra-window exclusive scan of deg.
__global__ __launch_bounds__(256) void k_offs(const int* __restrict__ bcount,
                                              const int* __restrict__ deg,
                                              float* __restrict__ dinv,
                                              int* __restrict__ offs,
                                              int* __restrict__ cur) {
    int b = blockIdx.x, t = threadIdx.x;
    int lane = t & 63, wid = t >> 6;
    // window base = sum_{w<b} bcount[w]
    int acc = 0;
    if (t < b) acc = bcount[t];
    if (t + 256 < b) acc += bcount[t + 256];
#pragma unroll
    for (int d = 32; d > 0; d >>= 1) acc += __shfl_xor(acc, d);
    __shared__ int ws[4];
    __shared__ int ps[4];
    if (lane == 0) ws[wid] = acc;
    __syncthreads();
    int base = ws[0] + ws[1] + ws[2] + ws[3];
    // per-node deg -> dinv + intra-window exclusive scan
    int node = b * 256 + t;
    int dv = (node < N_NODES) ? deg[node] : 0;
    if (node < N_NODES) dinv[node] = rsqrtf((float)(dv + 1));  // +1 self-loop
    int s = dv;
#pragma unroll
    for (int d = 1; d < 64; d <<= 1) { int nn = __shfl_up(s, d); if (lane >= d) s += nn; }
    if (lane == 63) ps[wid] = s;
    __syncthreads();
    if (t < 4) {
        int xx = ps[t];
#pragma unroll
        for (int d = 1; d < 4; d <<= 1) { int nn = __shfl_up(xx, d); if ((int)t >= d) xx += nn; }
        ps[t] = xx;
    }
    __syncthreads();
    int excl = s - dv + (wid ? ps[wid - 1] : 0) + base;
    if (node < N_NODES) {
        offs[node] = excl;
        cur[node] = excl;
    }
    if (b == NBUCK - 1 && t == 0) offs[N_NODES] = N_EDGES;
}

// ---------------- shared gemm body: u = bf16(inp @ W) (UNSCALED — dinv applied in agg) ----------
__device__ __forceinline__ void gemm_f32_body(int tile, const float* __restrict__ inp,
                                              const unsigned short* __restrict__ wp,
                                              unsigned short* __restrict__ u) {
    __shared__ unsigned short sW[32768];  // 64 KB: hi | lo (swizzled)
    {
        float4* d4 = (float4*)sW;
        const float4* s4 = (const float4*)wp;
#pragma unroll
        for (int i = 0; i < 16; ++i) d4[threadIdx.x + 256 * i] = s4[threadIdx.x + 256 * i];
    }
    __syncthreads();
    const int t = threadIdx.x;
    const int wv = t >> 6, L = t & 63;
    const int m = L & 15, q = L >> 4;
    const int r0 = tile * 64 + wv * 16;
    int arow = r0 + m;
    if (arow >= N_NODES) arow = N_NODES - 1;
    const float4* ap = (const float4*)(inp + (size_t)arow * 128);
    float4v acc[8];
#pragma unroll
    for (int c = 0; c < 8; ++c) acc[c] = (float4v){0.f, 0.f, 0.f, 0.f};
#pragma unroll
    for (int k0 = 0; k0 < 128; k0 += 32) {
        float4 f0 = ap[(k0 >> 2) + 2 * q];
        float4 f1 = ap[(k0 >> 2) + 2 * q + 1];
        float fa[8] = {f0.x, f0.y, f0.z, f0.w, f1.x, f1.y, f1.z, f1.w};
        short8 ah, al;
#pragma unroll
        for (int j = 0; j < 8; ++j) {
            unsigned ub = __float_as_uint(fa[j]);
            ah[j] = (short)(ub >> 16);
            float hif = __uint_as_float(ub & 0xFFFF0000u);
            al[j] = (short)f2bf(fa[j] - hif);
        }
        const int b = (k0 >> 3) + q;
#pragma unroll
        for (int c = 0; c < 8; ++c) {
            int ng = c * 16 + m;
            int elem = ng * 128 + 8 * ((b ^ ng) & 15);
            short8 bh = *(const short8*)&sW[elem];
            short8 bl = *(const short8*)&sW[16384 + elem];
            acc[c] = __builtin_amdgcn_mfma_f32_16x16x32_bf16(ah, bh, acc[c], 0, 0, 0);
            acc[c] = __builtin_amdgcn_mfma_f32_16x16x32_bf16(al, bh, acc[c], 0, 0, 0);
            acc[c] = __builtin_amdgcn_mfma_f32_16x16x32_bf16(ah, bl, acc[c], 0, 0, 0);
        }
    }
#pragma unroll
    for (int r = 0; r < 4; ++r) {
        int row = r0 + 4 * q + r;
        if (row < N_NODES) {
            unsigned short* up = u + (size_t)row * 128 + m;
#pragma unroll
            for (int c = 0; c < 8; ++c) up[c * 16] = f2bf(acc[c][r]);
        }
    }
}

// ---------------- dispatch 3: ALL gemm1 tiles (blocks 0..1562) + direct CSR fill (1563..1953) ----
// Replaces bucket_g1+bfill_g1: no pairs intermediate (-19 MB traffic), one dispatch fewer,
// gemm1 fully overlapped with the atomic fill. CSR order within a node differs from before —
// harmless (sum commutative; absmax has been quantization-floor-stable across 5 reorderings).
__global__ __launch_bounds__(256) void k_fill_g1(const int* __restrict__ src,
                                                 const int* __restrict__ dst,
                                                 int* __restrict__ cur,
                                                 int* __restrict__ csr,
                                                 const float* __restrict__ x,
                                                 const unsigned short* __restrict__ wp1,
                                                 unsigned short* __restrict__ u) {
    if (blockIdx.x < NTILES) {
        gemm_f32_body(blockIdx.x, x, wp1, u);
        return;
    }
    int fb = blockIdx.x - NTILES;
    int t = threadIdx.x;
    int e0 = fb * CHUNK;
#pragma unroll
    for (int j = 0; j < 16; ++j) {
        int e = e0 + j * 256 + t;
        if (e < N_EDGES) {
            int s = src[e], d = dst[e];
            int p = atomicAdd(&cur[d], 1);
            csr[p] = s;
        }
    }
}

// ---------------- fused agg1 + gemm2: u2 = bf16(relu(Ahat@u + b1) @ W2) ----------------
// 512 threads, 32 nodes/block (100000 = 3125*32 exact). LDS 16 KB (h rows only).
__global__ __launch_bounds__(512, 6) void k_agg1_g2(const unsigned int* __restrict__ u,
                                                    const int* __restrict__ offs,
                                                    const int* __restrict__ csr,
                                                    const float* __restrict__ dinv,
                                                    const float* __restrict__ bias,
                                                    const unsigned short* __restrict__ wp,
                                                    unsigned short* __restrict__ u2) {
    __shared__ float hS[32 * 128];         // 16 KB h rows (float4-group XOR swizzle)
    const int w = threadIdx.x >> 6;
    const int lane = threadIdx.x & 63;
    const int base = blockIdx.x * 32;

    // ---- phase 1: aggregation (4 nodes per wave, sequential) ----
    for (int n = 0; n < 4; ++n) {
        const int row = 4 * w + n;
        const int node = base + row;  // always < N_NODES
        int p = __builtin_amdgcn_readfirstlane(offs[node]);
        int e = __builtin_amdgcn_readfirstlane(offs[node + 1]);
        float dsf = dinv[node];
        unsigned int self = u[(size_t)node * 64 + lane];
        float ax0 = dsf * bf_lo(self), ay0 = dsf * bf_hi(self);
        float ax1 = 0.f, ay1 = 0.f, ax2 = 0.f, ay2 = 0.f, ax3 = 0.f, ay3 = 0.f;
        float ax4 = 0.f, ay4 = 0.f, ax5 = 0.f, ay5 = 0.f, ax6 = 0.f, ay6 = 0.f;
        float ax7 = 0.f, ay7 = 0.f;
        for (; p < e; p += 8) {
            int c0 = csr[p + 0], c1 = csr[p + 1], c2 = csr[p + 2], c3 = csr[p + 3];
            int c4 = csr[p + 4], c5 = csr[p + 5], c6 = csr[p + 6], c7 = csr[p + 7];
            int i0 = c0;
            int i1 = (p + 1 < e) ? c1 : N_NODES;
            int i2 = (p + 2 < e) ? c2 : N_NODES;
            int i3 = (p + 3 < e) ? c3 : N_NODES;
            int i4 = (p + 4 < e) ? c4 : N_NODES;
            int i5 = (p + 5 < e) ? c5 : N_NODES;
            int i6 = (p + 6 < e) ? c6 : N_NODES;
            int i7 = (p + 7 < e) ? c7 : N_NODES;
            float d0 = dinv[i0], d1 = dinv[i1], d2 = dinv[i2], d3 = dinv[i3];
            float d4 = dinv[i4], d5 = dinv[i5], d6 = dinv[i6], d7 = dinv[i7];
            unsigned v0 = (u + (size_t)i0 * 64)[lane];
            unsigned v1 = (u + (size_t)i1 * 64)[lane];
            unsigned v2 = (u + (size_t)i2 * 64)[lane];
            unsigned v3 = (u + (size_t)i3 * 64)[lane];
            unsigned v4 = (u + (size_t)i4 * 64)[lane];
            unsigned v5 = (u + (size_t)i5 * 64)[lane];
            unsigned v6 = (u + (size_t)i6 * 64)[lane];
            unsigned v7 = (u + (size_t)i7 * 64)[lane];
            ax0 = fmaf(d0, bf_lo(v0), ax0); ay0 = fmaf(d0, bf_hi(v0), ay0);
            ax1 = fmaf(d1, bf_lo(v1), ax1); ay1 = fmaf(d1, bf_hi(v1), ay1);
            ax2 = fmaf(d2, bf_lo(v2), ax2); ay2 = fmaf(d2, bf_hi(v2), ay2);
            ax3 = fmaf(d3, bf_lo(v3), ax3); ay3 = fmaf(d3, bf_hi(v3), ay3);
            ax4 = fmaf(d4, bf_lo(v4), ax4); ay4 = fmaf(d4, bf_hi(v4), ay4);
            ax5 = fmaf(d5, bf_lo(v5), ax5); ay5 = fmaf(d5, bf_hi(v5), ay5);
            ax6 = fmaf(d6, bf_lo(v6), ax6); ay6 = fmaf(d6, bf_hi(v6), ay6);
            ax7 = fmaf(d7, bf_lo(v7), ax7); ay7 = fmaf(d7, bf_hi(v7), ay7);
        }
        float2 b = ((const float2*)bias)[lane];
        float sx = ((ax0 + ax1) + (ax2 + ax3)) + ((ax4 + ax5) + (ax6 + ax7));
        float sy = ((ay0 + ay1) + (ay2 + ay3)) + ((ay4 + ay5) + (ay6 + ay7));
        float r0 = fmaxf(dsf * sx + b.x, 0.f);
        float r1 = fmaxf(dsf * sy + b.y, 0.f);
        // swizzled LDS write: k = 2*lane -> float4-group g = lane>>1, phys group = g ^ (row&7)
        int g4 = (lane >> 1) ^ (row & 7);
        float2* hp = (float2*)&hS[row * 128 + g4 * 4 + (lane & 1) * 2];
        *hp = (float2){r0, r1};
    }

    // ---- phase 2 setup + prologue W2 prefetch ----
    const int m = lane & 15, q = lane >> 4;
    const int rt = w >> 2;   // row-tile 0/1 (rows 16*rt..16*rt+15)
    const int cw = w & 3;    // column quarter (cols 32*cw..32*cw+31)
    const int arow = 16 * rt + m;
    const int ng0 = (2 * cw + 0) * 16 + m;
    const int ng1 = (2 * cw + 1) * 16 + m;
    short8 bh0, bl0, bh1, bl1;
    {
        int b = q;  // ks=0: b = 4*0 + q
        int e0 = ng0 * 128 + 8 * ((b ^ ng0) & 15);
        int e1 = ng1 * 128 + 8 * ((b ^ ng1) & 15);
        bh0 = *(const short8*)&wp[e0];
        bl0 = *(const short8*)&wp[16384 + e0];
        bh1 = *(const short8*)&wp[e1];
        bl1 = *(const short8*)&wp[16384 + e1];
    }
    __syncthreads();

    // ---- phase 2: u2[base..base+31] = bf16(h @ W2), 3-MFMA hi/lo ----
    float4v acc0 = (float4v){0.f, 0.f, 0.f, 0.f};
    float4v acc1 = (float4v){0.f, 0.f, 0.f, 0.f};
#pragma unroll
    for (int ks = 0; ks < 4; ++ks) {
        short8 nh0, nl0, nh1, nl1;
        if (ks < 3) {
            int b = 4 * (ks + 1) + q;
            int e0 = ng0 * 128 + 8 * ((b ^ ng0) & 15);
            int e1 = ng1 * 128 + 8 * ((b ^ ng1) & 15);
            nh0 = *(const short8*)&wp[e0];
            nl0 = *(const short8*)&wp[16384 + e0];
            nh1 = *(const short8*)&wp[e1];
            nl1 = *(const short8*)&wp[16384 + e1];
        }
        const int k0 = 32 * ks;
        int g1 = (k0 >> 2) + 2 * q;
        float4 f0 = *(const float4*)&hS[arow * 128 + ((g1 ^ (arow & 7)) << 2)];
        float4 f1 = *(const float4*)&hS[arow * 128 + (((g1 + 1) ^ (arow & 7)) << 2)];
        float fa[8] = {f0.x, f0.y, f0.z, f0.w, f1.x, f1.y, f1.z, f1.w};
        short8 ah, al;
#pragma unroll
        for (int j = 0; j < 8; ++j) {
            unsigned ub = __float_as_uint(fa[j]);
            ah[j] = (short)(ub >> 16);
            float hif = __uint_as_float(ub & 0xFFFF0000u);
            al[j] = (short)f2bf(fa[j] - hif);
        }
        acc0 = __builtin_amdgcn_mfma_f32_16x16x32_bf16(ah, bh0, acc0, 0, 0, 0);
        acc0 = __builtin_amdgcn_mfma_f32_16x16x32_bf16(al, bh0, acc0, 0, 0, 0);
        acc0 = __builtin_amdgcn_mfma_f32_16x16x32_bf16(ah, bl0, acc0, 0, 0, 0);
        acc1 = __builtin_amdgcn_mfma_f32_16x16x32_bf16(ah, bh1, acc1, 0, 0, 0);
        acc1 = __builtin_amdgcn_mfma_f32_16x16x32_bf16(al, bh1, acc1, 0, 0, 0);
        acc1 = __builtin_amdgcn_mfma_f32_16x16x32_bf16(ah, bl1, acc1, 0, 0, 0);
        if (ks < 3) {
            bh0 = nh0; bl0 = nl0; bh1 = nh1; bl1 = nl1;
        }
    }
#pragma unroll
    for (int r = 0; r < 4; ++r) {
        int row = 16 * rt + 4 * q + r;
        unsigned short* up = u2 + (size_t)(base + row) * 128 + m;
        up[(2 * cw + 0) * 16] = f2bf(acc0[r]);
        up[(2 * cw + 1) * 16] = f2bf(acc1[r]);
    }
}

// ---------------- agg2 (layer 2, pool-fused): project h2 onto Wl, per-node partial to pnode ----
__global__ __launch_bounds__(256) void k_agg2(const unsigned int* __restrict__ u,
                                              const int* __restrict__ offs,
                                              const int* __restrict__ csr,
                                              const float* __restrict__ dinv,
                                              const float* __restrict__ bias,
                                              const float* __restrict__ Wl,
                                              float* __restrict__ pnode) {
    int wid = threadIdx.x >> 6;
    int lane = threadIdx.x & 63;
    int node = __builtin_amdgcn_readfirstlane(blockIdx.x * 4 + wid);
    if (node >= N_NODES) return;
    int p = __builtin_amdgcn_readfirstlane(offs[node]);
    int e = __builtin_amdgcn_readfirstlane(offs[node + 1]);
    float dsf = dinv[node];
    unsigned int self = u[(size_t)node * 64 + lane];
    float ax0 = dsf * bf_lo(self), ay0 = dsf * bf_hi(self);
    float ax1 = 0.f, ay1 = 0.f, ax2 = 0.f, ay2 = 0.f, ax3 = 0.f, ay3 = 0.f;
    float ax4 = 0.f, ay4 = 0.f, ax5 = 0.f, ay5 = 0.f, ax6 = 0.f, ay6 = 0.f;
    float ax7 = 0.f, ay7 = 0.f;
    for (; p < e; p += 8) {
        int c0 = csr[p + 0], c1 = csr[p + 1], c2 = csr[p + 2], c3 = csr[p + 3];
        int c4 = csr[p + 4], c5 = csr[p + 5], c6 = csr[p + 6], c7 = csr[p + 7];
        int i0 = c0;
        int i1 = (p + 1 < e) ? c1 : N_NODES;
        int i2 = (p + 2 < e) ? c2 : N_NODES;
        int i3 = (p + 3 < e) ? c3 : N_NODES;
        int i4 = (p + 4 < e) ? c4 : N_NODES;
        int i5 = (p + 5 < e) ? c5 : N_NODES;
        int i6 = (p + 6 < e) ? c6 : N_NODES;
        int i7 = (p + 7 < e) ? c7 : N_NODES;
        float d0 = dinv[i0], d1 = dinv[i1], d2 = dinv[i2], d3 = dinv[i3];
        float d4 = dinv[i4], d5 = dinv[i5], d6 = dinv[i6], d7 = dinv[i7];
        unsigned v0 = (u + (size_t)i0 * 64)[lane];
        unsigned v1 = (u + (size_t)i1 * 64)[lane];
        unsigned v2 = (u + (size_t)i2 * 64)[lane];
        unsigned v3 = (u + (size_t)i3 * 64)[lane];
        unsigned v4 = (u + (size_t)i4 * 64)[lane];
        unsigned v5 = (u + (size_t)i5 * 64)[lane];
        unsigned v6 = (u + (size_t)i6 * 64)[lane];
        unsigned v7 = (u + (size_t)i7 * 64)[lane];
        ax0 = fmaf(d0, bf_lo(v0), ax0); ay0 = fmaf(d0, bf_hi(v0), ay0);
        ax1 = fmaf(d1, bf_lo(v1), ax1); ay1 = fmaf(d1, bf_hi(v1), ay1);
        ax2 = fmaf(d2, bf_lo(v2), ax2); ay2 = fmaf(d2, bf_hi(v2), ay2);
        ax3 = fmaf(d3, bf_lo(v3), ax3); ay3 = fmaf(d3, bf_hi(v3), ay3);
        ax4 = fmaf(d4, bf_lo(v4), ax4); ay4 = fmaf(d4, bf_hi(v4), ay4);
        ax5 = fmaf(d5, bf_lo(v5), ax5); ay5 = fmaf(d5, bf_hi(v5), ay5);
        ax6 = fmaf(d6, bf_lo(v6), ax6); ay6 = fmaf(d6, bf_hi(v6), ay6);
        ax7 = fmaf(d7, bf_lo(v7), ax7); ay7 = fmaf(d7, bf_hi(v7), ay7);
    }
    float2 b = ((const float2*)bias)[lane];
    float sx = ((ax0 + ax1) + (ax2 + ax3)) + ((ax4 + ax5) + (ax6 + ax7));
    float sy = ((ay0 + ay1) + (ay2 + ay3)) + ((ay4 + ay5) + (ay6 + ay7));
    float r0 = fmaxf(dsf * sx + b.x, 0.f);
    float r1 = fmaxf(dsf * sy + b.y, 0.f);
    // fused pool projection: lane holds channels (2*lane, 2*lane+1); Wl row-major [128][2].
    float2 wl0 = ((const float2*)Wl)[2 * lane];
    float2 wl1 = ((const float2*)Wl)[2 * lane + 1];
    float p0 = r0 * wl0.x + r1 * wl1.x;
    float p1 = r0 * wl0.y + r1 * wl1.y;
#pragma unroll
    for (int d = 32; d > 0; d >>= 1) {
        p0 += __shfl_xor(p0, d);
        p1 += __shfl_xor(p1, d);
    }
    if (lane == 0) {
        float2* pp = (float2*)pnode;
        pp[node] = (float2){p0, p1};
    }
}

// ---------------- finalize: out[g] = segsum(pnode)/max(cnt,1) + bl (1 wave per graph) ----------
__global__ __launch_bounds__(64) void k_fin(const float* __restrict__ pnode,
                                            const int* __restrict__ batch,
                                            const float* __restrict__ bl,
                                            float* __restrict__ out) {
    int g = blockIdx.x;
    int lane = threadIdx.x;
    __shared__ int sb[2];
    if (lane < 2) {
        int tgt = g + lane;
        int lo = 0, hi = N_NODES;
        while (lo < hi) { int m = (lo + hi) >> 1; if (batch[m] < tgt) lo = m + 1; else hi = m; }
        sb[lane] = lo;
    }
    __syncthreads();
    int s0 = sb[0], s1 = sb[1];
    const float2* pp = (const float2*)pnode;
    float p0 = 0.f, p1 = 0.f;
    for (int i = s0 + lane; i < s1; i += 64) {
        float2 v = pp[i];
        p0 += v.x;
        p1 += v.y;
    }
#pragma unroll
    for (int d = 32; d > 0; d >>= 1) {
        p0 += __shfl_xor(p0, d);
        p1 += __shfl_xor(p1, d);
    }
    if (lane == 0) {
        float inv = 1.f / fmaxf((float)(s1 - s0), 1.f);
        out[2 * g + 0] = p0 * inv + bl[0];
        out[2 * g + 1] = p1 * inv + bl[1];
    }
}

extern "C" void kernel_launch(void* const* d_in, const int* in_sizes, int n_in,
                              void* d_out, int out_size, void* d_ws, size_t ws_size,
                              hipStream_t stream) {
    const float* x  = (const float*)d_in[0];
    const int* ei   = (const int*)d_in[1];
    const int* batch = (const int*)d_in[2];
    const float* W1 = (const float*)d_in[3];
    const float* b1 = (const float*)d_in[4];
    const float* W2 = (const float*)d_in[5];
    const float* b2 = (const float*)d_in[6];
    const float* Wl = (const float*)d_in[7];
    const float* bl = (const float*)d_in[8];
    float* out = (float*)d_out;
    const int* src = ei;
    const int* dst = ei + N_EDGES;

    char* ws = (char*)d_ws;
    size_t o = 0;
    auto alloc = [&](size_t bytes) -> void* {
        o = (o + 255) & ~(size_t)255;
        void* p = ws + o;
        o += bytes;
        return p;
    };
    int* bcount = (int*)alloc((size_t)NBUCK * 4);
    int* deg    = (int*)alloc((size_t)N_NODES * 4);
    int* cur    = (int*)alloc((size_t)N_NODES * 4);
    float* dinv = (float*)alloc((size_t)(N_NODES + 1) * 4);  // +1 zero slot for tail
    int* offs   = (int*)alloc((size_t)(N_NODES + 1) * 4);
    unsigned short* wp1 = (unsigned short*)alloc(65536);
    unsigned short* wp2 = (unsigned short*)alloc(65536);
    float* pnode = (float*)alloc((size_t)N_NODES * 2 * 4);
    int* csr    = (int*)alloc((size_t)(N_EDGES + 8) * 4);               // +8 pad for unroll reads
    unsigned short* u  = (unsigned short*)alloc((size_t)(N_NODES + 1) * 128 * 2);  // +1 zero row
    unsigned short* u2 = (unsigned short*)alloc((size_t)(N_NODES + 1) * 128 * 2);  // +1 zero row

    hipMemsetAsync(bcount, 0, (size_t)NBUCK * 4, stream);
    hipMemsetAsync(deg, 0, (size_t)N_NODES * 4, stream);
    k_prep_hist<<<384, 256, 0, stream>>>(W1, W2, wp1, wp2, dst, bcount, deg,
                                         (unsigned int*)(u + (size_t)N_NODES * 128),
                                         (unsigned int*)(u2 + (size_t)N_NODES * 128), dinv);
    k_offs<<<NBUCK, 256, 0, stream>>>(bcount, deg, dinv, offs, cur);
    k_fill_g1<<<NTILES + NBUCK, 256, 0, stream>>>(src, dst, cur, csr, x, wp1, u);

    k_agg1_g2<<<N_NODES / 32, 512, 0, stream>>>((const unsigned int*)u, offs, csr, dinv, b1,
                                                wp2, u2);
    k_agg2<<<(N_NODES + 3) / 4, 256, 0, stream>>>((const unsigned int*)u2, offs, csr, dinv, b2,
                                                  Wl, pnode);

    k_fin<<<N_GRAPHS, 64, 0, stream>>>(pnode, batch, bl, out);
}

// Round 9
// 305.869 us; speedup vs baseline: 1.4889x; 1.4889x over previous
//
#include <hip/hip_runtime.h>
#include <hip/hip_bf16.h>

#define N_NODES 100000
#define N_EDGES 1600000
#define FEAT 128
#define N_GRAPHS 1024
#define NBUCK 391   // ceil(N_NODES/256) windows of 256 nodes (bucket = dst >> 8)
#define CHUNK 4096  // edges per k_bucket block
#define NT128 782   // ceil(N_NODES/128) gemm row tiles (128-row tiles)
#define G1A 391     // gemm1 tiles overlapped with bucket
#define G1B 391     // gemm1 tiles overlapped with bfill

typedef short short8 __attribute__((ext_vector_type(8)));
typedef float float4v __attribute__((ext_vector_type(4)));

static __device__ inline unsigned short f2bf(float f) {
    __hip_bfloat16 b = __float2bfloat16(f);
    unsigned short r;
    __builtin_memcpy(&r, &b, 2);
    return r;
}
static __device__ inline float bf_lo(unsigned int v) { return __uint_as_float(v << 16); }
static __device__ inline float bf_hi(unsigned int v) { return __uint_as_float(v & 0xFFFF0000u); }

// ---------------- dispatch 1: W-split prep (blocks 0..127) + dst histogram (blocks 128..383) ----------
__global__ __launch_bounds__(256) void k_prep_hist(const float* __restrict__ W1,
                                                   const float* __restrict__ W2,
                                                   unsigned short* __restrict__ wp1,
                                                   unsigned short* __restrict__ wp2,
                                                   const int* __restrict__ dst,
                                                   int* __restrict__ bcount,
                                                   unsigned int* __restrict__ udummy,
                                                   unsigned int* __restrict__ u2dummy,
                                                   float* __restrict__ dinv) {
    int bid = blockIdx.x;
    if (bid < 128) {
        const float* W = (bid < 64) ? W1 : W2;
        unsigned short* wp = (bid < 64) ? wp1 : wp2;
        int t = (bid & 63) * 256 + threadIdx.x;  // 0..16383
        int k = t >> 7, n = t & 127;
        float w = W[k * 128 + n];
        unsigned ub = __float_as_uint(w);
        unsigned short hi = (unsigned short)(ub >> 16);  // truncation split
        float hif = __uint_as_float(ub & 0xFFFF0000u);
        unsigned short lo = f2bf(w - hif);               // RNE residual
        int sidx = n * 128 + ((k & 7) | (8 * (((k >> 3) ^ n) & 15)));
        wp[sidx] = hi;
        wp[16384 + sidx] = lo;
        if (bid == 0) {
            if (threadIdx.x < 64) udummy[threadIdx.x] = 0;
            else if (threadIdx.x < 128) u2dummy[threadIdx.x - 64] = 0;
            else if (threadIdx.x == 128) dinv[N_NODES] = 0.f;
        }
    } else {
        __shared__ int h[NBUCK];
        for (int i = threadIdx.x; i < NBUCK; i += 256) h[i] = 0;
        __syncthreads();
        int hb = bid - 128;
        for (int e = hb * 256 + threadIdx.x; e < N_EDGES; e += 256 * 256)
            atomicAdd(&h[dst[e] >> 8], 1);
        __syncthreads();
        for (int i = threadIdx.x; i < NBUCK; i += 256) {
            int c = h[i];
            if (c) atomicAdd(&bcount[i], c);
        }
    }
}

// ---------------- dispatch 2: exclusive scan of 391 bucket counts (single block) ----------------
// bbase doubles as the CSR window base (wbase==bbase: per-bucket deg sum == bucket edge count).
__global__ __launch_bounds__(512) void k_scan391(const int* __restrict__ in,
                                                 int* __restrict__ base,
                                                 int* __restrict__ cur,
                                                 int* __restrict__ tail) {
    int t = threadIdx.x;
    int v = (t < NBUCK) ? in[t] : 0;
    int lane = t & 63, wid = t >> 6;
    int s = v;
#pragma unroll
    for (int d = 1; d < 64; d <<= 1) { int n = __shfl_up(s, d); if (lane >= d) s += n; }
    __shared__ int ws[8];
    if (lane == 63) ws[wid] = s;
    __syncthreads();
    if (t < 8) {
        int x = ws[t];
#pragma unroll
        for (int d = 1; d < 8; d <<= 1) { int n = __shfl_up(x, d); if ((int)t >= d) x += n; }
        ws[t] = x;
    }
    __syncthreads();
    int excl = s - v + (wid ? ws[wid - 1] : 0);
    if (t < NBUCK) {
        base[t] = excl;
        cur[t] = excl;
    }
    if (t == 0) tail[0] = N_EDGES;
}

// ---------------- shared gemm body: u = bf16(inp @ W), 128-row tiles ----------------
// R9: 128-row tile (was 64) — each wave computes 32 rows x 128 cols; B fragments (bh,bl) loaded
// once per (k0,c) from LDS are reused by BOTH row-frags (192 MFMA / 16 B-loads = 2x reuse vs 64-row).
// m93-ladder analogy (bigger tile, more acc/wave = 1.51x). Same sW swizzle, same 3-MFMA hi/lo math.
__device__ __forceinline__ void gemm_f32_body(int tile, const float* __restrict__ inp,
                                              const unsigned short* __restrict__ wp,
                                              unsigned short* __restrict__ u) {
    __shared__ unsigned short sW[32768];  // 64 KB: hi | lo (swizzled)
    {
        float4* d4 = (float4*)sW;
        const float4* s4 = (const float4*)wp;
#pragma unroll
        for (int i = 0; i < 16; ++i) d4[threadIdx.x + 256 * i] = s4[threadIdx.x + 256 * i];
    }
    __syncthreads();
    const int t = threadIdx.x;
    const int w = t >> 6, L = t & 63;
    const int m = L & 15, q = L >> 4;
    const int r0 = tile * 128 + w * 32;
    int ar0 = r0 + m;
    int ar1 = r0 + 16 + m;
    if (ar0 >= N_NODES) ar0 = N_NODES - 1;
    if (ar1 >= N_NODES) ar1 = N_NODES - 1;
    const float4* ap0 = (const float4*)(inp + (size_t)ar0 * 128);
    const float4* ap1 = (const float4*)(inp + (size_t)ar1 * 128);
    float4v acc0[8], acc1[8];
#pragma unroll
    for (int c = 0; c < 8; ++c) {
        acc0[c] = (float4v){0.f, 0.f, 0.f, 0.f};
        acc1[c] = (float4v){0.f, 0.f, 0.f, 0.f};
    }
#pragma unroll
    for (int k0 = 0; k0 < 128; k0 += 32) {
        short8 ah0, al0, ah1, al1;
        {
            float4 f0 = ap0[(k0 >> 2) + 2 * q];
            float4 f1 = ap0[(k0 >> 2) + 2 * q + 1];
            float fa[8] = {f0.x, f0.y, f0.z, f0.w, f1.x, f1.y, f1.z, f1.w};
#pragma unroll
            for (int j = 0; j < 8; ++j) {
                unsigned ub = __float_as_uint(fa[j]);
                ah0[j] = (short)(ub >> 16);
                float hif = __uint_as_float(ub & 0xFFFF0000u);
                al0[j] = (short)f2bf(fa[j] - hif);
            }
        }
        {
            float4 f0 = ap1[(k0 >> 2) + 2 * q];
            float4 f1 = ap1[(k0 >> 2) + 2 * q + 1];
            float fa[8] = {f0.x, f0.y, f0.z, f0.w, f1.x, f1.y, f1.z, f1.w};
#pragma unroll
            for (int j = 0; j < 8; ++j) {
                unsigned ub = __float_as_uint(fa[j]);
                ah1[j] = (short)(ub >> 16);
                float hif = __uint_as_float(ub & 0xFFFF0000u);
                al1[j] = (short)f2bf(fa[j] - hif);
            }
        }
        const int b = (k0 >> 3) + q;
#pragma unroll
        for (int c = 0; c < 8; ++c) {
            int ng = c * 16 + m;
            int elem = ng * 128 + 8 * ((b ^ ng) & 15);
            short8 bh = *(const short8*)&sW[elem];
            short8 bl = *(const short8*)&sW[16384 + elem];
            acc0[c] = __builtin_amdgcn_mfma_f32_16x16x32_bf16(ah0, bh, acc0[c], 0, 0, 0);
            acc0[c] = __builtin_amdgcn_mfma_f32_16x16x32_bf16(al0, bh, acc0[c], 0, 0, 0);
            acc0[c] = __builtin_amdgcn_mfma_f32_16x16x32_bf16(ah0, bl, acc0[c], 0, 0, 0);
            acc1[c] = __builtin_amdgcn_mfma_f32_16x16x32_bf16(ah1, bh, acc1[c], 0, 0, 0);
            acc1[c] = __builtin_amdgcn_mfma_f32_16x16x32_bf16(al1, bh, acc1[c], 0, 0, 0);
            acc1[c] = __builtin_amdgcn_mfma_f32_16x16x32_bf16(ah1, bl, acc1[c], 0, 0, 0);
        }
    }
#pragma unroll
    for (int r = 0; r < 4; ++r) {
        int row0 = r0 + 4 * q + r;
        if (row0 < N_NODES) {
            unsigned short* up = u + (size_t)row0 * 128 + m;
#pragma unroll
            for (int c = 0; c < 8; ++c) up[c * 16] = f2bf(acc0[c][r]);
        }
        int row1 = r0 + 16 + 4 * q + r;
        if (row1 < N_NODES) {
            unsigned short* up = u + (size_t)row1 * 128 + m;
#pragma unroll
            for (int c = 0; c < 8; ++c) up[c * 16] = f2bf(acc1[c][r]);
        }
    }
}

// ---------------- dispatch 3: bucket binning (blocks 0..390) + gemm1 tiles 0..390 ----------------
__global__ __launch_bounds__(256) void k_bucket_g1(const int* __restrict__ src,
                                                   const int* __restrict__ dst,
                                                   int* __restrict__ bcur,
                                                   unsigned int* __restrict__ pairs,
                                                   const float* __restrict__ x,
                                                   const unsigned short* __restrict__ wp1,
                                                   unsigned short* __restrict__ u) {
    if (blockIdx.x >= NBUCK) {
        gemm_f32_body(blockIdx.x - NBUCK, x, wp1, u);
        return;
    }
    __shared__ int cnt[NBUCK];
    __shared__ int basebuf[NBUCK];
    int t = threadIdx.x;
    int e0 = blockIdx.x * CHUNK;
    for (int i = t; i < NBUCK; i += 256) cnt[i] = 0;
    __syncthreads();
    unsigned pk[16]; int bk[16];
#pragma unroll
    for (int j = 0; j < 16; ++j) {
        int e = e0 + j * 256 + t;
        if (e < N_EDGES) {
            int s = src[e], d = dst[e];
            bk[j] = d >> 8;
            pk[j] = ((unsigned)s << 8) | (unsigned)(d & 255);
            atomicAdd(&cnt[bk[j]], 1);
        } else bk[j] = -1;
    }
    __syncthreads();
    for (int i = t; i < NBUCK; i += 256) {
        int c = cnt[i];
        basebuf[i] = c ? atomicAdd(&bcur[i], c) : 0;
        cnt[i] = 0;
    }
    __syncthreads();
#pragma unroll
    for (int j = 0; j < 16; ++j) {
        if (bk[j] >= 0) {
            int p = basebuf[bk[j]] + atomicAdd(&cnt[bk[j]], 1);
            pairs[p] = pk[j];
        }
    }
}

// ---------------- dispatch 4: fused deg+dinv+offs+csr fill (blocks 0..390) + gemm1 tiles 391..781 ----
__global__ __launch_bounds__(256) void k_bfill_g1(const unsigned int* __restrict__ pairs,
                                                  const int* __restrict__ bbase,
                                                  const int* __restrict__ bcount,
                                                  float* __restrict__ dinv,
                                                  int* __restrict__ offs,
                                                  int* __restrict__ csr,
                                                  const float* __restrict__ x,
                                                  const unsigned short* __restrict__ wp1,
                                                  unsigned short* __restrict__ u) {
    if (blockIdx.x >= NBUCK) {
        gemm_f32_body(blockIdx.x - NBUCK + G1A, x, wp1, u);
        return;
    }
    __shared__ int degl[256];
    __shared__ int lcur[256];
    __shared__ int ws[4];
    int b = blockIdx.x, t = threadIdx.x;
    degl[t] = 0;
    __syncthreads();
    int s0 = bbase[b], n = bcount[b];
    for (int i = t; i < n; i += 256) atomicAdd(&degl[pairs[s0 + i] & 255u], 1);
    __syncthreads();
    int node = b * 256 + t;
    int dv = degl[t];
    if (node < N_NODES) dinv[node] = rsqrtf((float)(dv + 1));  // +1 self-loop
    int lane = t & 63, wid = t >> 6;
    int s = dv;
#pragma unroll
    for (int d = 1; d < 64; d <<= 1) { int nn = __shfl_up(s, d); if (lane >= d) s += nn; }
    if (lane == 63) ws[wid] = s;
    __syncthreads();
    if (t < 4) {
        int xx = ws[t];
#pragma unroll
        for (int d = 1; d < 4; d <<= 1) { int nn = __shfl_up(xx, d); if ((int)t >= d) xx += nn; }
        ws[t] = xx;
    }
    __syncthreads();
    int excl = s - dv + (wid ? ws[wid - 1] : 0) + bbase[b];  // wbase == bbase
    if (node < N_NODES) offs[node] = excl;
    lcur[t] = excl;
    __syncthreads();
    for (int i = t; i < n; i += 256) {
        unsigned pr = pairs[s0 + i];
        int p = atomicAdd(&lcur[pr & 255u], 1);
        csr[p] = (int)(pr >> 8);
    }
}

// ---------------- fused agg1 + gemm2: u2 = bf16(relu(Ahat@u + b1) @ W2) ----------------
// 512 threads, 32 nodes/block (100000 = 3125*32 exact). LDS 16 KB (h rows only).
__global__ __launch_bounds__(512, 6) void k_agg1_g2(const unsigned int* __restrict__ u,
                                                    const int* __restrict__ offs,
                                                    const int* __restrict__ csr,
                                                    const float* __restrict__ dinv,
                                                    const float* __restrict__ bias,
                                                    const unsigned short* __restrict__ wp,
                                                    unsigned short* __restrict__ u2) {
    __shared__ float hS[32 * 128];         // 16 KB h rows (float4-group XOR swizzle)
    const int w = threadIdx.x >> 6;
    const int lane = threadIdx.x & 63;
    const int base = blockIdx.x * 32;

    // ---- phase 1: aggregation (4 nodes per wave, sequential) ----
    for (int n = 0; n < 4; ++n) {
        const int row = 4 * w + n;
        const int node = base + row;  // always < N_NODES
        int p = __builtin_amdgcn_readfirstlane(offs[node]);
        int e = __builtin_amdgcn_readfirstlane(offs[node + 1]);
        float dsf = dinv[node];
        unsigned int self = u[(size_t)node * 64 + lane];
        float ax0 = dsf * bf_lo(self), ay0 = dsf * bf_hi(self);
        float ax1 = 0.f, ay1 = 0.f, ax2 = 0.f, ay2 = 0.f, ax3 = 0.f, ay3 = 0.f;
        float ax4 = 0.f, ay4 = 0.f, ax5 = 0.f, ay5 = 0.f, ax6 = 0.f, ay6 = 0.f;
        float ax7 = 0.f, ay7 = 0.f;
        for (; p < e; p += 8) {
            int c0 = csr[p + 0], c1 = csr[p + 1], c2 = csr[p + 2], c3 = csr[p + 3];
            int c4 = csr[p + 4], c5 = csr[p + 5], c6 = csr[p + 6], c7 = csr[p + 7];
            int i0 = c0;
            int i1 = (p + 1 < e) ? c1 : N_NODES;
            int i2 = (p + 2 < e) ? c2 : N_NODES;
            int i3 = (p + 3 < e) ? c3 : N_NODES;
            int i4 = (p + 4 < e) ? c4 : N_NODES;
            int i5 = (p + 5 < e) ? c5 : N_NODES;
            int i6 = (p + 6 < e) ? c6 : N_NODES;
            int i7 = (p + 7 < e) ? c7 : N_NODES;
            float d0 = dinv[i0], d1 = dinv[i1], d2 = dinv[i2], d3 = dinv[i3];
            float d4 = dinv[i4], d5 = dinv[i5], d6 = dinv[i6], d7 = dinv[i7];
            unsigned v0 = (u + (size_t)i0 * 64)[lane];
            unsigned v1 = (u + (size_t)i1 * 64)[lane];
            unsigned v2 = (u + (size_t)i2 * 64)[lane];
            unsigned v3 = (u + (size_t)i3 * 64)[lane];
            unsigned v4 = (u + (size_t)i4 * 64)[lane];
            unsigned v5 = (u + (size_t)i5 * 64)[lane];
            unsigned v6 = (u + (size_t)i6 * 64)[lane];
            unsigned v7 = (u + (size_t)i7 * 64)[lane];
            ax0 = fmaf(d0, bf_lo(v0), ax0); ay0 = fmaf(d0, bf_hi(v0), ay0);
            ax1 = fmaf(d1, bf_lo(v1), ax1); ay1 = fmaf(d1, bf_hi(v1), ay1);
            ax2 = fmaf(d2, bf_lo(v2), ax2); ay2 = fmaf(d2, bf_hi(v2), ay2);
            ax3 = fmaf(d3, bf_lo(v3), ax3); ay3 = fmaf(d3, bf_hi(v3), ay3);
            ax4 = fmaf(d4, bf_lo(v4), ax4); ay4 = fmaf(d4, bf_hi(v4), ay4);
            ax5 = fmaf(d5, bf_lo(v5), ax5); ay5 = fmaf(d5, bf_hi(v5), ay5);
            ax6 = fmaf(d6, bf_lo(v6), ax6); ay6 = fmaf(d6, bf_hi(v6), ay6);
            ax7 = fmaf(d7, bf_lo(v7), ax7); ay7 = fmaf(d7, bf_hi(v7), ay7);
        }
        float2 b = ((const float2*)bias)[lane];
        float sx = ((ax0 + ax1) + (ax2 + ax3)) + ((ax4 + ax5) + (ax6 + ax7));
        float sy = ((ay0 + ay1) + (ay2 + ay3)) + ((ay4 + ay5) + (ay6 + ay7));
        float r0 = fmaxf(dsf * sx + b.x, 0.f);
        float r1 = fmaxf(dsf * sy + b.y, 0.f);
        // swizzled LDS write: k = 2*lane -> float4-group g = lane>>1, phys group = g ^ (row&7)
        int g4 = (lane >> 1) ^ (row & 7);
        float2* hp = (float2*)&hS[row * 128 + g4 * 4 + (lane & 1) * 2];
        *hp = (float2){r0, r1};
    }

    // ---- phase 2 setup + prologue W2 prefetch ----
    const int m = lane & 15, q = lane >> 4;
    const int rt = w >> 2;   // row-tile 0/1 (rows 16*rt..16*rt+15)
    const int cw = w & 3;    // column quarter (cols 32*cw..32*cw+31)
    const int arow = 16 * rt + m;
    const int ng0 = (2 * cw + 0) * 16 + m;
    const int ng1 = (2 * cw + 1) * 16 + m;
    short8 bh0, bl0, bh1, bl1;
    {
        int b = q;  // ks=0: b = 4*0 + q
        int e0 = ng0 * 128 + 8 * ((b ^ ng0) & 15);
        int e1 = ng1 * 128 + 8 * ((b ^ ng1) & 15);
        bh0 = *(const short8*)&wp[e0];
        bl0 = *(const short8*)&wp[16384 + e0];
        bh1 = *(const short8*)&wp[e1];
        bl1 = *(const short8*)&wp[16384 + e1];
    }
    __syncthreads();

    // ---- phase 2: u2[base..base+31] = bf16(h @ W2), 3-MFMA hi/lo ----
    float4v acc0 = (float4v){0.f, 0.f, 0.f, 0.f};
    float4v acc1 = (float4v){0.f, 0.f, 0.f, 0.f};
#pragma unroll
    for (int ks = 0; ks < 4; ++ks) {
        short8 nh0, nl0, nh1, nl1;
        if (ks < 3) {
            int b = 4 * (ks + 1) + q;
            int e0 = ng0 * 128 + 8 * ((b ^ ng0) & 15);
            int e1 = ng1 * 128 + 8 * ((b ^ ng1) & 15);
            nh0 = *(const short8*)&wp[e0];
            nl0 = *(const short8*)&wp[16384 + e0];
            nh1 = *(const short8*)&wp[e1];
            nl1 = *(const short8*)&wp[16384 + e1];
        }
        const int k0 = 32 * ks;
        int g1 = (k0 >> 2) + 2 * q;
        float4 f0 = *(const float4*)&hS[arow * 128 + ((g1 ^ (arow & 7)) << 2)];
        float4 f1 = *(const float4*)&hS[arow * 128 + (((g1 + 1) ^ (arow & 7)) << 2)];
        float fa[8] = {f0.x, f0.y, f0.z, f0.w, f1.x, f1.y, f1.z, f1.w};
        short8 ah, al;
#pragma unroll
        for (int j = 0; j < 8; ++j) {
            unsigned ub = __float_as_uint(fa[j]);
            ah[j] = (short)(ub >> 16);
            float hif = __uint_as_float(ub & 0xFFFF0000u);
            al[j] = (short)f2bf(fa[j] - hif);
        }
        acc0 = __builtin_amdgcn_mfma_f32_16x16x32_bf16(ah, bh0, acc0, 0, 0, 0);
        acc0 = __builtin_amdgcn_mfma_f32_16x16x32_bf16(al, bh0, acc0, 0, 0, 0);
        acc0 = __builtin_amdgcn_mfma_f32_16x16x32_bf16(ah, bl0, acc0, 0, 0, 0);
        acc1 = __builtin_amdgcn_mfma_f32_16x16x32_bf16(ah, bh1, acc1, 0, 0, 0);
        acc1 = __builtin_amdgcn_mfma_f32_16x16x32_bf16(al, bh1, acc1, 0, 0, 0);
        acc1 = __builtin_amdgcn_mfma_f32_16x16x32_bf16(ah, bl1, acc1, 0, 0, 0);
        if (ks < 3) {
            bh0 = nh0; bl0 = nl0; bh1 = nh1; bl1 = nl1;
        }
    }
#pragma unroll
    for (int r = 0; r < 4; ++r) {
        int row = 16 * rt + 4 * q + r;
        unsigned short* up = u2 + (size_t)(base + row) * 128 + m;
        up[(2 * cw + 0) * 16] = f2bf(acc0[r]);
        up[(2 * cw + 1) * 16] = f2bf(acc1[r]);
    }
}

// ---------------- agg2 (layer 2, pool-fused): project h2 onto Wl, per-node partial to pnode ----
__global__ __launch_bounds__(256) void k_agg2(const unsigned int* __restrict__ u,
                                              const int* __restrict__ offs,
                                              const int* __restrict__ csr,
                                              const float* __restrict__ dinv,
                                              const float* __restrict__ bias,
                                              const float* __restrict__ Wl,
                                              float* __restrict__ pnode) {
    int wid = threadIdx.x >> 6;
    int lane = threadIdx.x & 63;
    int node = __builtin_amdgcn_readfirstlane(blockIdx.x * 4 + wid);
    if (node >= N_NODES) return;
    int p = __builtin_amdgcn_readfirstlane(offs[node]);
    int e = __builtin_amdgcn_readfirstlane(offs[node + 1]);
    float dsf = dinv[node];
    unsigned int self = u[(size_t)node * 64 + lane];
    float ax0 = dsf * bf_lo(self), ay0 = dsf * bf_hi(self);
    float ax1 = 0.f, ay1 = 0.f, ax2 = 0.f, ay2 = 0.f, ax3 = 0.f, ay3 = 0.f;
    float ax4 = 0.f, ay4 = 0.f, ax5 = 0.f, ay5 = 0.f, ax6 = 0.f, ay6 = 0.f;
    float ax7 = 0.f, ay7 = 0.f;
    for (; p < e; p += 8) {
        int c0 = csr[p + 0], c1 = csr[p + 1], c2 = csr[p + 2], c3 = csr[p + 3];
        int c4 = csr[p + 4], c5 = csr[p + 5], c6 = csr[p + 6], c7 = csr[p + 7];
        int i0 = c0;
        int i1 = (p + 1 < e) ? c1 : N_NODES;
        int i2 = (p + 2 < e) ? c2 : N_NODES;
        int i3 = (p + 3 < e) ? c3 : N_NODES;
        int i4 = (p + 4 < e) ? c4 : N_NODES;
        int i5 = (p + 5 < e) ? c5 : N_NODES;
        int i6 = (p + 6 < e) ? c6 : N_NODES;
        int i7 = (p + 7 < e) ? c7 : N_NODES;
        float d0 = dinv[i0], d1 = dinv[i1], d2 = dinv[i2], d3 = dinv[i3];
        float d4 = dinv[i4], d5 = dinv[i5], d6 = dinv[i6], d7 = dinv[i7];
        unsigned v0 = (u + (size_t)i0 * 64)[lane];
        unsigned v1 = (u + (size_t)i1 * 64)[lane];
        unsigned v2 = (u + (size_t)i2 * 64)[lane];
        unsigned v3 = (u + (size_t)i3 * 64)[lane];
        unsigned v4 = (u + (size_t)i4 * 64)[lane];
        unsigned v5 = (u + (size_t)i5 * 64)[lane];
        unsigned v6 = (u + (size_t)i6 * 64)[lane];
        unsigned v7 = (u + (size_t)i7 * 64)[lane];
        ax0 = fmaf(d0, bf_lo(v0), ax0); ay0 = fmaf(d0, bf_hi(v0), ay0);
        ax1 = fmaf(d1, bf_lo(v1), ax1); ay1 = fmaf(d1, bf_hi(v1), ay1);
        ax2 = fmaf(d2, bf_lo(v2), ax2); ay2 = fmaf(d2, bf_hi(v2), ay2);
        ax3 = fmaf(d3, bf_lo(v3), ax3); ay3 = fmaf(d3, bf_hi(v3), ay3);
        ax4 = fmaf(d4, bf_lo(v4), ax4); ay4 = fmaf(d4, bf_hi(v4), ay4);
        ax5 = fmaf(d5, bf_lo(v5), ax5); ay5 = fmaf(d5, bf_hi(v5), ay5);
        ax6 = fmaf(d6, bf_lo(v6), ax6); ay6 = fmaf(d6, bf_hi(v6), ay6);
        ax7 = fmaf(d7, bf_lo(v7), ax7); ay7 = fmaf(d7, bf_hi(v7), ay7);
    }
    float2 b = ((const float2*)bias)[lane];
    float sx = ((ax0 + ax1) + (ax2 + ax3)) + ((ax4 + ax5) + (ax6 + ax7));
    float sy = ((ay0 + ay1) + (ay2 + ay3)) + ((ay4 + ay5) + (ay6 + ay7));
    float r0 = fmaxf(dsf * sx + b.x, 0.f);
    float r1 = fmaxf(dsf * sy + b.y, 0.f);
    // fused pool projection: lane holds channels (2*lane, 2*lane+1); Wl row-major [128][2].
    float2 wl0 = ((const float2*)Wl)[2 * lane];
    float2 wl1 = ((const float2*)Wl)[2 * lane + 1];
    float p0 = r0 * wl0.x + r1 * wl1.x;
    float p1 = r0 * wl0.y + r1 * wl1.y;
#pragma unroll
    for (int d = 32; d > 0; d >>= 1) {
        p0 += __shfl_xor(p0, d);
        p1 += __shfl_xor(p1, d);
    }
    if (lane == 0) {
        float2* pp = (float2*)pnode;
        pp[node] = (float2){p0, p1};
    }
}

// ---------------- finalize: out[g] = segsum(pnode)/max(cnt,1) + bl (1 wave per graph) ----------
__global__ __launch_bounds__(64) void k_fin(const float* __restrict__ pnode,
                                            const int* __restrict__ batch,
                                            const float* __restrict__ bl,
                                            float* __restrict__ out) {
    int g = blockIdx.x;
    int lane = threadIdx.x;
    __shared__ int sb[2];
    if (lane < 2) {
        int tgt = g + lane;
        int lo = 0, hi = N_NODES;
        while (lo < hi) { int m = (lo + hi) >> 1; if (batch[m] < tgt) lo = m + 1; else hi = m; }
        sb[lane] = lo;
    }
    __syncthreads();
    int s0 = sb[0], s1 = sb[1];
    const float2* pp = (const float2*)pnode;
    float p0 = 0.f, p1 = 0.f;
    for (int i = s0 + lane; i < s1; i += 64) {
        float2 v = pp[i];
        p0 += v.x;
        p1 += v.y;
    }
#pragma unroll
    for (int d = 32; d > 0; d >>= 1) {
        p0 += __shfl_xor(p0, d);
        p1 += __shfl_xor(p1, d);
    }
    if (lane == 0) {
        float inv = 1.f / fmaxf((float)(s1 - s0), 1.f);
        out[2 * g + 0] = p0 * inv + bl[0];
        out[2 * g + 1] = p1 * inv + bl[1];
    }
}

extern "C" void kernel_launch(void* const* d_in, const int* in_sizes, int n_in,
                              void* d_out, int out_size, void* d_ws, size_t ws_size,
                              hipStream_t stream) {
    const float* x  = (const float*)d_in[0];
    const int* ei   = (const int*)d_in[1];
    const int* batch = (const int*)d_in[2];
    const float* W1 = (const float*)d_in[3];
    const float* b1 = (const float*)d_in[4];
    const float* W2 = (const float*)d_in[5];
    const float* b2 = (const float*)d_in[6];
    const float* Wl = (const float*)d_in[7];
    const float* bl = (const float*)d_in[8];
    float* out = (float*)d_out;
    const int* src = ei;
    const int* dst = ei + N_EDGES;

    char* ws = (char*)d_ws;
    size_t o = 0;
    auto alloc = [&](size_t bytes) -> void* {
        o = (o + 255) & ~(size_t)255;
        void* p = ws + o;
        o += bytes;
        return p;
    };
    int* bcount = (int*)alloc((size_t)NBUCK * 4);
    int* bbase  = (int*)alloc((size_t)NBUCK * 4);
    int* bcur   = (int*)alloc((size_t)NBUCK * 4);
    float* dinv = (float*)alloc((size_t)(N_NODES + 1) * 4);  // +1 zero slot for tail
    int* offs   = (int*)alloc((size_t)(N_NODES + 1) * 4);
    unsigned short* wp1 = (unsigned short*)alloc(65536);
    unsigned short* wp2 = (unsigned short*)alloc(65536);
    float* pnode = (float*)alloc((size_t)N_NODES * 2 * 4);
    unsigned int* pairs = (unsigned int*)alloc((size_t)N_EDGES * 4);
    int* csr    = (int*)alloc((size_t)(N_EDGES + 8) * 4);               // +8 pad for unroll reads
    unsigned short* u  = (unsigned short*)alloc((size_t)(N_NODES + 1) * 128 * 2);  // +1 zero row
    unsigned short* u2 = (unsigned short*)alloc((size_t)(N_NODES + 1) * 128 * 2);  // +1 zero row

    hipMemsetAsync(bcount, 0, (size_t)NBUCK * 4, stream);
    k_prep_hist<<<384, 256, 0, stream>>>(W1, W2, wp1, wp2, dst, bcount,
                                         (unsigned int*)(u + (size_t)N_NODES * 128),
                                         (unsigned int*)(u2 + (size_t)N_NODES * 128), dinv);
    k_scan391<<<1, 512, 0, stream>>>(bcount, bbase, bcur, &offs[N_NODES]);
    k_bucket_g1<<<NBUCK + G1A, 256, 0, stream>>>(src, dst, bcur, pairs, x, wp1, u);
    k_bfill_g1<<<NBUCK + G1B, 256, 0, stream>>>(pairs, bbase, bcount, dinv, offs, csr, x, wp1, u);

    k_agg1_g2<<<N_NODES / 32, 512, 0, stream>>>((const unsigned int*)u, offs, csr, dinv, b1,
                                                wp2, u2);
    k_agg2<<<(N_NODES + 3) / 4, 256, 0, stream>>>((const unsigned int*)u2, offs, csr, dinv, b2,
                                                  Wl, pnode);

    k_fin<<<N_GRAPHS, 64, 0, stream>>>(pnode, batch, bl, out);
}

// Round 10
// 303.770 us; speedup vs baseline: 1.4992x; 1.0069x over previous
//
#include <hip/hip_runtime.h>
#include <hip/hip_bf16.h>

#define N_NODES 100000
#define N_EDGES 1600000
#define FEAT 128
#define N_GRAPHS 1024
#define NBUCK 391   // ceil(N_NODES/256) windows of 256 nodes (bucket = dst >> 8)
#define CHUNK 4096  // edges per k_bucket block
#define NT128 782   // ceil(N_NODES/128) gemm row tiles (128-row tiles)
#define G1A 391     // gemm1 tiles overlapped with bucket
#define G1B 391     // gemm1 tiles overlapped with bfill

typedef short short8 __attribute__((ext_vector_type(8)));
typedef float float4v __attribute__((ext_vector_type(4)));

static __device__ inline unsigned short f2bf(float f) {
    __hip_bfloat16 b = __float2bfloat16(f);
    unsigned short r;
    __builtin_memcpy(&r, &b, 2);
    return r;
}
static __device__ inline float bf_lo(unsigned int v) { return __uint_as_float(v << 16); }
static __device__ inline float bf_hi(unsigned int v) { return __uint_as_float(v & 0xFFFF0000u); }

// ---------------- dispatch 1: W-split prep (blocks 0..127) + dst histogram (blocks 128..383) ----------
__global__ __launch_bounds__(256) void k_prep_hist(const float* __restrict__ W1,
                                                   const float* __restrict__ W2,
                                                   unsigned short* __restrict__ wp1,
                                                   unsigned short* __restrict__ wp2,
                                                   const int* __restrict__ dst,
                                                   int* __restrict__ bcount,
                                                   unsigned int* __restrict__ udummy,
                                                   unsigned int* __restrict__ u2dummy,
                                                   float* __restrict__ dinv) {
    int bid = blockIdx.x;
    if (bid < 128) {
        const float* W = (bid < 64) ? W1 : W2;
        unsigned short* wp = (bid < 64) ? wp1 : wp2;
        int t = (bid & 63) * 256 + threadIdx.x;  // 0..16383
        int k = t >> 7, n = t & 127;
        float w = W[k * 128 + n];
        unsigned ub = __float_as_uint(w);
        unsigned short hi = (unsigned short)(ub >> 16);  // truncation split
        float hif = __uint_as_float(ub & 0xFFFF0000u);
        unsigned short lo = f2bf(w - hif);               // RNE residual
        int sidx = n * 128 + ((k & 7) | (8 * (((k >> 3) ^ n) & 15)));
        wp[sidx] = hi;
        wp[16384 + sidx] = lo;
        if (bid == 0) {
            if (threadIdx.x < 64) udummy[threadIdx.x] = 0;
            else if (threadIdx.x < 128) u2dummy[threadIdx.x - 64] = 0;
            else if (threadIdx.x == 128) dinv[N_NODES] = 0.f;
        }
    } else {
        __shared__ int h[NBUCK];
        for (int i = threadIdx.x; i < NBUCK; i += 256) h[i] = 0;
        __syncthreads();
        int hb = bid - 128;
        for (int e = hb * 256 + threadIdx.x; e < N_EDGES; e += 256 * 256)
            atomicAdd(&h[dst[e] >> 8], 1);
        __syncthreads();
        for (int i = threadIdx.x; i < NBUCK; i += 256) {
            int c = h[i];
            if (c) atomicAdd(&bcount[i], c);
        }
    }
}

// ---------------- dispatch 2: exclusive scan of 391 bucket counts (single block) ----------------
// bbase doubles as the CSR window base (wbase==bbase: per-bucket deg sum == bucket edge count).
__global__ __launch_bounds__(512) void k_scan391(const int* __restrict__ in,
                                                 int* __restrict__ base,
                                                 int* __restrict__ cur,
                                                 int* __restrict__ tail) {
    int t = threadIdx.x;
    int v = (t < NBUCK) ? in[t] : 0;
    int lane = t & 63, wid = t >> 6;
    int s = v;
#pragma unroll
    for (int d = 1; d < 64; d <<= 1) { int n = __shfl_up(s, d); if (lane >= d) s += n; }
    __shared__ int ws[8];
    if (lane == 63) ws[wid] = s;
    __syncthreads();
    if (t < 8) {
        int x = ws[t];
#pragma unroll
        for (int d = 1; d < 8; d <<= 1) { int n = __shfl_up(x, d); if ((int)t >= d) x += n; }
        ws[t] = x;
    }
    __syncthreads();
    int excl = s - v + (wid ? ws[wid - 1] : 0);
    if (t < NBUCK) {
        base[t] = excl;
        cur[t] = excl;
    }
    if (t == 0) tail[0] = N_EDGES;
}

// ---------------- shared gemm body: u = bf16(inp @ W), 128-row tiles ----------------
// 128-row tile — each wave computes 32 rows x 128 cols; B fragments (bh,bl) loaded once per
// (k0,c) from LDS are reused by BOTH row-frags (2x reuse vs 64-row). Proven +8us in r9.
__device__ __forceinline__ void gemm_f32_body(int tile, const float* __restrict__ inp,
                                              const unsigned short* __restrict__ wp,
                                              unsigned short* __restrict__ u) {
    __shared__ unsigned short sW[32768];  // 64 KB: hi | lo (swizzled)
    {
        float4* d4 = (float4*)sW;
        const float4* s4 = (const float4*)wp;
#pragma unroll
        for (int i = 0; i < 16; ++i) d4[threadIdx.x + 256 * i] = s4[threadIdx.x + 256 * i];
    }
    __syncthreads();
    const int t = threadIdx.x;
    const int w = t >> 6, L = t & 63;
    const int m = L & 15, q = L >> 4;
    const int r0 = tile * 128 + w * 32;
    int ar0 = r0 + m;
    int ar1 = r0 + 16 + m;
    if (ar0 >= N_NODES) ar0 = N_NODES - 1;
    if (ar1 >= N_NODES) ar1 = N_NODES - 1;
    const float4* ap0 = (const float4*)(inp + (size_t)ar0 * 128);
    const float4* ap1 = (const float4*)(inp + (size_t)ar1 * 128);
    float4v acc0[8], acc1[8];
#pragma unroll
    for (int c = 0; c < 8; ++c) {
        acc0[c] = (float4v){0.f, 0.f, 0.f, 0.f};
        acc1[c] = (float4v){0.f, 0.f, 0.f, 0.f};
    }
#pragma unroll
    for (int k0 = 0; k0 < 128; k0 += 32) {
        short8 ah0, al0, ah1, al1;
        {
            float4 f0 = ap0[(k0 >> 2) + 2 * q];
            float4 f1 = ap0[(k0 >> 2) + 2 * q + 1];
            float fa[8] = {f0.x, f0.y, f0.z, f0.w, f1.x, f1.y, f1.z, f1.w};
#pragma unroll
            for (int j = 0; j < 8; ++j) {
                unsigned ub = __float_as_uint(fa[j]);
                ah0[j] = (short)(ub >> 16);
                float hif = __uint_as_float(ub & 0xFFFF0000u);
                al0[j] = (short)f2bf(fa[j] - hif);
            }
        }
        {
            float4 f0 = ap1[(k0 >> 2) + 2 * q];
            float4 f1 = ap1[(k0 >> 2) + 2 * q + 1];
            float fa[8] = {f0.x, f0.y, f0.z, f0.w, f1.x, f1.y, f1.z, f1.w};
#pragma unroll
            for (int j = 0; j < 8; ++j) {
                unsigned ub = __float_as_uint(fa[j]);
                ah1[j] = (short)(ub >> 16);
                float hif = __uint_as_float(ub & 0xFFFF0000u);
                al1[j] = (short)f2bf(fa[j] - hif);
            }
        }
        const int b = (k0 >> 3) + q;
#pragma unroll
        for (int c = 0; c < 8; ++c) {
            int ng = c * 16 + m;
            int elem = ng * 128 + 8 * ((b ^ ng) & 15);
            short8 bh = *(const short8*)&sW[elem];
            short8 bl = *(const short8*)&sW[16384 + elem];
            acc0[c] = __builtin_amdgcn_mfma_f32_16x16x32_bf16(ah0, bh, acc0[c], 0, 0, 0);
            acc0[c] = __builtin_amdgcn_mfma_f32_16x16x32_bf16(al0, bh, acc0[c], 0, 0, 0);
            acc0[c] = __builtin_amdgcn_mfma_f32_16x16x32_bf16(ah0, bl, acc0[c], 0, 0, 0);
            acc1[c] = __builtin_amdgcn_mfma_f32_16x16x32_bf16(ah1, bh, acc1[c], 0, 0, 0);
            acc1[c] = __builtin_amdgcn_mfma_f32_16x16x32_bf16(al1, bh, acc1[c], 0, 0, 0);
            acc1[c] = __builtin_amdgcn_mfma_f32_16x16x32_bf16(ah1, bl, acc1[c], 0, 0, 0);
        }
    }
#pragma unroll
    for (int r = 0; r < 4; ++r) {
        int row0 = r0 + 4 * q + r;
        if (row0 < N_NODES) {
            unsigned short* up = u + (size_t)row0 * 128 + m;
#pragma unroll
            for (int c = 0; c < 8; ++c) up[c * 16] = f2bf(acc0[c][r]);
        }
        int row1 = r0 + 16 + 4 * q + r;
        if (row1 < N_NODES) {
            unsigned short* up = u + (size_t)row1 * 128 + m;
#pragma unroll
            for (int c = 0; c < 8; ++c) up[c * 16] = f2bf(acc1[c][r]);
        }
    }
}

// ---------------- dispatch 3: bucket binning (blocks 0..390) + gemm1 tiles 0..390 ----------------
__global__ __launch_bounds__(256) void k_bucket_g1(const int* __restrict__ src,
                                                   const int* __restrict__ dst,
                                                   int* __restrict__ bcur,
                                                   unsigned int* __restrict__ pairs,
                                                   const float* __restrict__ x,
                                                   const unsigned short* __restrict__ wp1,
                                                   unsigned short* __restrict__ u) {
    if (blockIdx.x >= NBUCK) {
        gemm_f32_body(blockIdx.x - NBUCK, x, wp1, u);
        return;
    }
    __shared__ int cnt[NBUCK];
    __shared__ int basebuf[NBUCK];
    int t = threadIdx.x;
    int e0 = blockIdx.x * CHUNK;
    for (int i = t; i < NBUCK; i += 256) cnt[i] = 0;
    __syncthreads();
    unsigned pk[16]; int bk[16];
#pragma unroll
    for (int j = 0; j < 16; ++j) {
        int e = e0 + j * 256 + t;
        if (e < N_EDGES) {
            int s = src[e], d = dst[e];
            bk[j] = d >> 8;
            pk[j] = ((unsigned)s << 8) | (unsigned)(d & 255);
            atomicAdd(&cnt[bk[j]], 1);
        } else bk[j] = -1;
    }
    __syncthreads();
    for (int i = t; i < NBUCK; i += 256) {
        int c = cnt[i];
        basebuf[i] = c ? atomicAdd(&bcur[i], c) : 0;
        cnt[i] = 0;
    }
    __syncthreads();
#pragma unroll
    for (int j = 0; j < 16; ++j) {
        if (bk[j] >= 0) {
            int p = basebuf[bk[j]] + atomicAdd(&cnt[bk[j]], 1);
            pairs[p] = pk[j];
        }
    }
}

// ---------------- dispatch 4: fused deg+dinv+offs+csr fill (blocks 0..390) + gemm1 tiles 391..781 ----
__global__ __launch_bounds__(256) void k_bfill_g1(const unsigned int* __restrict__ pairs,
                                                  const int* __restrict__ bbase,
                                                  const int* __restrict__ bcount,
                                                  float* __restrict__ dinv,
                                                  int* __restrict__ offs,
                                                  int* __restrict__ csr,
                                                  const float* __restrict__ x,
                                                  const unsigned short* __restrict__ wp1,
                                                  unsigned short* __restrict__ u) {
    if (blockIdx.x >= NBUCK) {
        gemm_f32_body(blockIdx.x - NBUCK + G1A, x, wp1, u);
        return;
    }
    __shared__ int degl[256];
    __shared__ int lcur[256];
    __shared__ int ws[4];
    int b = blockIdx.x, t = threadIdx.x;
    degl[t] = 0;
    __syncthreads();
    int s0 = bbase[b], n = bcount[b];
    for (int i = t; i < n; i += 256) atomicAdd(&degl[pairs[s0 + i] & 255u], 1);
    __syncthreads();
    int node = b * 256 + t;
    int dv = degl[t];
    if (node < N_NODES) dinv[node] = rsqrtf((float)(dv + 1));  // +1 self-loop
    int lane = t & 63, wid = t >> 6;
    int s = dv;
#pragma unroll
    for (int d = 1; d < 64; d <<= 1) { int nn = __shfl_up(s, d); if (lane >= d) s += nn; }
    if (lane == 63) ws[wid] = s;
    __syncthreads();
    if (t < 4) {
        int xx = ws[t];
#pragma unroll
        for (int d = 1; d < 4; d <<= 1) { int nn = __shfl_up(xx, d); if ((int)t >= d) xx += nn; }
        ws[t] = xx;
    }
    __syncthreads();
    int excl = s - dv + (wid ? ws[wid - 1] : 0) + bbase[b];  // wbase == bbase
    if (node < N_NODES) offs[node] = excl;
    lcur[t] = excl;
    __syncthreads();
    for (int i = t; i < n; i += 256) {
        unsigned pr = pairs[s0 + i];
        int p = atomicAdd(&lcur[pr & 255u], 1);
        csr[p] = (int)(pr >> 8);
    }
}

// ---------------- fused agg1 + gemm2: u2 = bf16(relu(Ahat@u + b1) @ W2) ----------------
// R10: 256 threads / 16 nodes per block (100000 = 6250*16 exact), LDS 8 KB -> 8 blocks/CU
// (wave-slot-capped) = 32 waves/CU (100% occ). R9's 512-thread/32-node shape sat at ~2.75
// blocks/CU, so the phase-1->2 barrier idled up to 8 waves behind the slowest edge-loop with
// little co-resident work to absorb it (hbm 2.8 vs plain agg's 3.95 TB/s). Smaller blocks:
// a barrier now idles 4 of 32 resident waves, and imbalance is max-over-4 not max-over-8.
// Phase 2 = same code with rt=0, cw=w (4 waves x 2 col-tiles of the 16x128 output).
__global__ __launch_bounds__(256, 8) void k_agg1_g2(const unsigned int* __restrict__ u,
                                                    const int* __restrict__ offs,
                                                    const int* __restrict__ csr,
                                                    const float* __restrict__ dinv,
                                                    const float* __restrict__ bias,
                                                    const unsigned short* __restrict__ wp,
                                                    unsigned short* __restrict__ u2) {
    __shared__ float hS[16 * 128];         // 8 KB h rows (float4-group XOR swizzle)
    const int w = threadIdx.x >> 6;
    const int lane = threadIdx.x & 63;
    const int base = blockIdx.x * 16;

    // ---- phase 1: aggregation (4 nodes per wave, sequential) ----
    for (int n = 0; n < 4; ++n) {
        const int row = 4 * w + n;
        const int node = base + row;  // always < N_NODES (6250*16 exact)
        int p = __builtin_amdgcn_readfirstlane(offs[node]);
        int e = __builtin_amdgcn_readfirstlane(offs[node + 1]);
        float dsf = dinv[node];
        unsigned int self = u[(size_t)node * 64 + lane];
        float ax0 = dsf * bf_lo(self), ay0 = dsf * bf_hi(self);
        float ax1 = 0.f, ay1 = 0.f, ax2 = 0.f, ay2 = 0.f, ax3 = 0.f, ay3 = 0.f;
        float ax4 = 0.f, ay4 = 0.f, ax5 = 0.f, ay5 = 0.f, ax6 = 0.f, ay6 = 0.f;
        float ax7 = 0.f, ay7 = 0.f;
        for (; p < e; p += 8) {
            int c0 = csr[p + 0], c1 = csr[p + 1], c2 = csr[p + 2], c3 = csr[p + 3];
            int c4 = csr[p + 4], c5 = csr[p + 5], c6 = csr[p + 6], c7 = csr[p + 7];
            int i0 = c0;
            int i1 = (p + 1 < e) ? c1 : N_NODES;
            int i2 = (p + 2 < e) ? c2 : N_NODES;
            int i3 = (p + 3 < e) ? c3 : N_NODES;
            int i4 = (p + 4 < e) ? c4 : N_NODES;
            int i5 = (p + 5 < e) ? c5 : N_NODES;
            int i6 = (p + 6 < e) ? c6 : N_NODES;
            int i7 = (p + 7 < e) ? c7 : N_NODES;
            float d0 = dinv[i0], d1 = dinv[i1], d2 = dinv[i2], d3 = dinv[i3];
            float d4 = dinv[i4], d5 = dinv[i5], d6 = dinv[i6], d7 = dinv[i7];
            unsigned v0 = (u + (size_t)i0 * 64)[lane];
            unsigned v1 = (u + (size_t)i1 * 64)[lane];
            unsigned v2 = (u + (size_t)i2 * 64)[lane];
            unsigned v3 = (u + (size_t)i3 * 64)[lane];
            unsigned v4 = (u + (size_t)i4 * 64)[lane];
            unsigned v5 = (u + (size_t)i5 * 64)[lane];
            unsigned v6 = (u + (size_t)i6 * 64)[lane];
            unsigned v7 = (u + (size_t)i7 * 64)[lane];
            ax0 = fmaf(d0, bf_lo(v0), ax0); ay0 = fmaf(d0, bf_hi(v0), ay0);
            ax1 = fmaf(d1, bf_lo(v1), ax1); ay1 = fmaf(d1, bf_hi(v1), ay1);
            ax2 = fmaf(d2, bf_lo(v2), ax2); ay2 = fmaf(d2, bf_hi(v2), ay2);
            ax3 = fmaf(d3, bf_lo(v3), ax3); ay3 = fmaf(d3, bf_hi(v3), ay3);
            ax4 = fmaf(d4, bf_lo(v4), ax4); ay4 = fmaf(d4, bf_hi(v4), ay4);
            ax5 = fmaf(d5, bf_lo(v5), ax5); ay5 = fmaf(d5, bf_hi(v5), ay5);
            ax6 = fmaf(d6, bf_lo(v6), ax6); ay6 = fmaf(d6, bf_hi(v6), ay6);
            ax7 = fmaf(d7, bf_lo(v7), ax7); ay7 = fmaf(d7, bf_hi(v7), ay7);
        }
        float2 b = ((const float2*)bias)[lane];
        float sx = ((ax0 + ax1) + (ax2 + ax3)) + ((ax4 + ax5) + (ax6 + ax7));
        float sy = ((ay0 + ay1) + (ay2 + ay3)) + ((ay4 + ay5) + (ay6 + ay7));
        float r0 = fmaxf(dsf * sx + b.x, 0.f);
        float r1 = fmaxf(dsf * sy + b.y, 0.f);
        // swizzled LDS write: k = 2*lane -> float4-group g = lane>>1, phys group = g ^ (row&7)
        int g4 = (lane >> 1) ^ (row & 7);
        float2* hp = (float2*)&hS[row * 128 + g4 * 4 + (lane & 1) * 2];
        *hp = (float2){r0, r1};
    }

    // ---- phase 2 setup + prologue W2 prefetch ----
    const int m = lane & 15, q = lane >> 4;
    const int cw = w;        // wave = column quarter (cols 32*w..32*w+31); single row-tile
    const int arow = m;
    const int ng0 = (2 * cw + 0) * 16 + m;
    const int ng1 = (2 * cw + 1) * 16 + m;
    short8 bh0, bl0, bh1, bl1;
    {
        int b = q;  // ks=0: b = 4*0 + q
        int e0 = ng0 * 128 + 8 * ((b ^ ng0) & 15);
        int e1 = ng1 * 128 + 8 * ((b ^ ng1) & 15);
        bh0 = *(const short8*)&wp[e0];
        bl0 = *(const short8*)&wp[16384 + e0];
        bh1 = *(const short8*)&wp[e1];
        bl1 = *(const short8*)&wp[16384 + e1];
    }
    __syncthreads();

    // ---- phase 2: u2[base..base+15] = bf16(h @ W2), 3-MFMA hi/lo ----
    float4v acc0 = (float4v){0.f, 0.f, 0.f, 0.f};
    float4v acc1 = (float4v){0.f, 0.f, 0.f, 0.f};
#pragma unroll
    for (int ks = 0; ks < 4; ++ks) {
        short8 nh0, nl0, nh1, nl1;
        if (ks < 3) {
            int b = 4 * (ks + 1) + q;
            int e0 = ng0 * 128 + 8 * ((b ^ ng0) & 15);
            int e1 = ng1 * 128 + 8 * ((b ^ ng1) & 15);
            nh0 = *(const short8*)&wp[e0];
            nl0 = *(const short8*)&wp[16384 + e0];
            nh1 = *(const short8*)&wp[e1];
            nl1 = *(const short8*)&wp[16384 + e1];
        }
        const int k0 = 32 * ks;
        int g1 = (k0 >> 2) + 2 * q;
        float4 f0 = *(const float4*)&hS[arow * 128 + ((g1 ^ (arow & 7)) << 2)];
        float4 f1 = *(const float4*)&hS[arow * 128 + (((g1 + 1) ^ (arow & 7)) << 2)];
        float fa[8] = {f0.x, f0.y, f0.z, f0.w, f1.x, f1.y, f1.z, f1.w};
        short8 ah, al;
#pragma unroll
        for (int j = 0; j < 8; ++j) {
            unsigned ub = __float_as_uint(fa[j]);
            ah[j] = (short)(ub >> 16);
            float hif = __uint_as_float(ub & 0xFFFF0000u);
            al[j] = (short)f2bf(fa[j] - hif);
        }
        acc0 = __builtin_amdgcn_mfma_f32_16x16x32_bf16(ah, bh0, acc0, 0, 0, 0);
        acc0 = __builtin_amdgcn_mfma_f32_16x16x32_bf16(al, bh0, acc0, 0, 0, 0);
        acc0 = __builtin_amdgcn_mfma_f32_16x16x32_bf16(ah, bl0, acc0, 0, 0, 0);
        acc1 = __builtin_amdgcn_mfma_f32_16x16x32_bf16(ah, bh1, acc1, 0, 0, 0);
        acc1 = __builtin_amdgcn_mfma_f32_16x16x32_bf16(al, bh1, acc1, 0, 0, 0);
        acc1 = __builtin_amdgcn_mfma_f32_16x16x32_bf16(ah, bl1, acc1, 0, 0, 0);
        if (ks < 3) {
            bh0 = nh0; bl0 = nl0; bh1 = nh1; bl1 = nl1;
        }
    }
#pragma unroll
    for (int r = 0; r < 4; ++r) {
        int row = 4 * q + r;
        unsigned short* up = u2 + (size_t)(base + row) * 128 + m;
        up[(2 * cw + 0) * 16] = f2bf(acc0[r]);
        up[(2 * cw + 1) * 16] = f2bf(acc1[r]);
    }
}

// ---------------- agg2 (layer 2, pool-fused): project h2 onto Wl, per-node partial to pnode ----
__global__ __launch_bounds__(256) void k_agg2(const unsigned int* __restrict__ u,
                                              const int* __restrict__ offs,
                                              const int* __restrict__ csr,
                                              const float* __restrict__ dinv,
                                              const float* __restrict__ bias,
                                              const float* __restrict__ Wl,
                                              float* __restrict__ pnode) {
    int wid = threadIdx.x >> 6;
    int lane = threadIdx.x & 63;
    int node = __builtin_amdgcn_readfirstlane(blockIdx.x * 4 + wid);
    if (node >= N_NODES) return;
    int p = __builtin_amdgcn_readfirstlane(offs[node]);
    int e = __builtin_amdgcn_readfirstlane(offs[node + 1]);
    float dsf = dinv[node];
    unsigned int self = u[(size_t)node * 64 + lane];
    float ax0 = dsf * bf_lo(self), ay0 = dsf * bf_hi(self);
    float ax1 = 0.f, ay1 = 0.f, ax2 = 0.f, ay2 = 0.f, ax3 = 0.f, ay3 = 0.f;
    float ax4 = 0.f, ay4 = 0.f, ax5 = 0.f, ay5 = 0.f, ax6 = 0.f, ay6 = 0.f;
    float ax7 = 0.f, ay7 = 0.f;
    for (; p < e; p += 8) {
        int c0 = csr[p + 0], c1 = csr[p + 1], c2 = csr[p + 2], c3 = csr[p + 3];
        int c4 = csr[p + 4], c5 = csr[p + 5], c6 = csr[p + 6], c7 = csr[p + 7];
        int i0 = c0;
        int i1 = (p + 1 < e) ? c1 : N_NODES;
        int i2 = (p + 2 < e) ? c2 : N_NODES;
        int i3 = (p + 3 < e) ? c3 : N_NODES;
        int i4 = (p + 4 < e) ? c4 : N_NODES;
        int i5 = (p + 5 < e) ? c5 : N_NODES;
        int i6 = (p + 6 < e) ? c6 : N_NODES;
        int i7 = (p + 7 < e) ? c7 : N_NODES;
        float d0 = dinv[i0], d1 = dinv[i1], d2 = dinv[i2], d3 = dinv[i3];
        float d4 = dinv[i4], d5 = dinv[i5], d6 = dinv[i6], d7 = dinv[i7];
        unsigned v0 = (u + (size_t)i0 * 64)[lane];
        unsigned v1 = (u + (size_t)i1 * 64)[lane];
        unsigned v2 = (u + (size_t)i2 * 64)[lane];
        unsigned v3 = (u + (size_t)i3 * 64)[lane];
        unsigned v4 = (u + (size_t)i4 * 64)[lane];
        unsigned v5 = (u + (size_t)i5 * 64)[lane];
        unsigned v6 = (u + (size_t)i6 * 64)[lane];
        unsigned v7 = (u + (size_t)i7 * 64)[lane];
        ax0 = fmaf(d0, bf_lo(v0), ax0); ay0 = fmaf(d0, bf_hi(v0), ay0);
        ax1 = fmaf(d1, bf_lo(v1), ax1); ay1 = fmaf(d1, bf_hi(v1), ay1);
        ax2 = fmaf(d2, bf_lo(v2), ax2); ay2 = fmaf(d2, bf_hi(v2), ay2);
        ax3 = fmaf(d3, bf_lo(v3), ax3); ay3 = fmaf(d3, bf_hi(v3), ay3);
        ax4 = fmaf(d4, bf_lo(v4), ax4); ay4 = fmaf(d4, bf_hi(v4), ay4);
        ax5 = fmaf(d5, bf_lo(v5), ax5); ay5 = fmaf(d5, bf_hi(v5), ay5);
        ax6 = fmaf(d6, bf_lo(v6), ax6); ay6 = fmaf(d6, bf_hi(v6), ay6);
        ax7 = fmaf(d7, bf_lo(v7), ax7); ay7 = fmaf(d7, bf_hi(v7), ay7);
    }
    float2 b = ((const float2*)bias)[lane];
    float sx = ((ax0 + ax1) + (ax2 + ax3)) + ((ax4 + ax5) + (ax6 + ax7));
    float sy = ((ay0 + ay1) + (ay2 + ay3)) + ((ay4 + ay5) + (ay6 + ay7));
    float r0 = fmaxf(dsf * sx + b.x, 0.f);
    float r1 = fmaxf(dsf * sy + b.y, 0.f);
    // fused pool projection: lane holds channels (2*lane, 2*lane+1); Wl row-major [128][2].
    float2 wl0 = ((const float2*)Wl)[2 * lane];
    float2 wl1 = ((const float2*)Wl)[2 * lane + 1];
    float p0 = r0 * wl0.x + r1 * wl1.x;
    float p1 = r0 * wl0.y + r1 * wl1.y;
#pragma unroll
    for (int d = 32; d > 0; d >>= 1) {
        p0 += __shfl_xor(p0, d);
        p1 += __shfl_xor(p1, d);
    }
    if (lane == 0) {
        float2* pp = (float2*)pnode;
        pp[node] = (float2){p0, p1};
    }
}

// ---------------- finalize: out[g] = segsum(pnode)/max(cnt,1) + bl (1 wave per graph) ----------
__global__ __launch_bounds__(64) void k_fin(const float* __restrict__ pnode,
                                            const int* __restrict__ batch,
                                            const float* __restrict__ bl,
                                            float* __restrict__ out) {
    int g = blockIdx.x;
    int lane = threadIdx.x;
    __shared__ int sb[2];
    if (lane < 2) {
        int tgt = g + lane;
        int lo = 0, hi = N_NODES;
        while (lo < hi) { int m = (lo + hi) >> 1; if (batch[m] < tgt) lo = m + 1; else hi = m; }
        sb[lane] = lo;
    }
    __syncthreads();
    int s0 = sb[0], s1 = sb[1];
    const float2* pp = (const float2*)pnode;
    float p0 = 0.f, p1 = 0.f;
    for (int i = s0 + lane; i < s1; i += 64) {
        float2 v = pp[i];
        p0 += v.x;
        p1 += v.y;
    }
#pragma unroll
    for (int d = 32; d > 0; d >>= 1) {
        p0 += __shfl_xor(p0, d);
        p1 += __shfl_xor(p1, d);
    }
    if (lane == 0) {
        float inv = 1.f / fmaxf((float)(s1 - s0), 1.f);
        out[2 * g + 0] = p0 * inv + bl[0];
        out[2 * g + 1] = p1 * inv + bl[1];
    }
}

extern "C" void kernel_launch(void* const* d_in, const int* in_sizes, int n_in,
                              void* d_out, int out_size, void* d_ws, size_t ws_size,
                              hipStream_t stream) {
    const float* x  = (const float*)d_in[0];
    const int* ei   = (const int*)d_in[1];
    const int* batch = (const int*)d_in[2];
    const float* W1 = (const float*)d_in[3];
    const float* b1 = (const float*)d_in[4];
    const float* W2 = (const float*)d_in[5];
    const float* b2 = (const float*)d_in[6];
    const float* Wl = (const float*)d_in[7];
    const float* bl = (const float*)d_in[8];
    float* out = (float*)d_out;
    const int* src = ei;
    const int* dst = ei + N_EDGES;

    char* ws = (char*)d_ws;
    size_t o = 0;
    auto alloc = [&](size_t bytes) -> void* {
        o = (o + 255) & ~(size_t)255;
        void* p = ws + o;
        o += bytes;
        return p;
    };
    int* bcount = (int*)alloc((size_t)NBUCK * 4);
    int* bbase  = (int*)alloc((size_t)NBUCK * 4);
    int* bcur   = (int*)alloc((size_t)NBUCK * 4);
    float* dinv = (float*)alloc((size_t)(N_NODES + 1) * 4);  // +1 zero slot for tail
    int* offs   = (int*)alloc((size_t)(N_NODES + 1) * 4);
    unsigned short* wp1 = (unsigned short*)alloc(65536);
    unsigned short* wp2 = (unsigned short*)alloc(65536);
    float* pnode = (float*)alloc((size_t)N_NODES * 2 * 4);
    unsigned int* pairs = (unsigned int*)alloc((size_t)N_EDGES * 4);
    int* csr    = (int*)alloc((size_t)(N_EDGES + 8) * 4);               // +8 pad for unroll reads
    unsigned short* u  = (unsigned short*)alloc((size_t)(N_NODES + 1) * 128 * 2);  // +1 zero row
    unsigned short* u2 = (unsigned short*)alloc((size_t)(N_NODES + 1) * 128 * 2);  // +1 zero row

    hipMemsetAsync(bcount, 0, (size_t)NBUCK * 4, stream);
    k_prep_hist<<<384, 256, 0, stream>>>(W1, W2, wp1, wp2, dst, bcount,
                                         (unsigned int*)(u + (size_t)N_NODES * 128),
                                         (unsigned int*)(u2 + (size_t)N_NODES * 128), dinv);
    k_scan391<<<1, 512, 0, stream>>>(bcount, bbase, bcur, &offs[N_NODES]);
    k_bucket_g1<<<NBUCK + G1A, 256, 0, stream>>>(src, dst, bcur, pairs, x, wp1, u);
    k_bfill_g1<<<NBUCK + G1B, 256, 0, stream>>>(pairs, bbase, bcount, dinv, offs, csr, x, wp1, u);

    k_agg1_g2<<<N_NODES / 16, 256, 0, stream>>>((const unsigned int*)u, offs, csr, dinv, b1,
                                                wp2, u2);
    k_agg2<<<(N_NODES + 3) / 4, 256, 0, stream>>>((const unsigned int*)u2, offs, csr, dinv, b2,
                                                  Wl, pnode);

    k_fin<<<N_GRAPHS, 64, 0, stream>>>(pnode, batch, bl, out);
}